// Round 6
// baseline (187.103 us; speedup 1.0000x reference)
//
#include <hip/hip_runtime.h>
#include <cstdint>
#include <cstddef>

typedef __fp16 half8 __attribute__((ext_vector_type(8)));
typedef float  f32x4 __attribute__((ext_vector_type(4)));

#define BATCH 8192
#define INDIM 2048
#define OUTD  512
#define NC    256      // 16 trees * 16 (15 nodes + 1 zero pad)
#define BM    32       // rows per block -> 256 blocks = 1/CU

__device__ __forceinline__ half8 cvt8(float4 a, float4 b) {
  half8 h;
  h[0] = (__fp16)a.x; h[1] = (__fp16)a.y; h[2] = (__fp16)a.z; h[3] = (__fp16)a.w;
  h[4] = (__fp16)b.x; h[5] = (__fp16)b.y; h[6] = (__fp16)b.z; h[7] = (__fp16)b.w;
  return h;
}

// ---- prep: WrT[16t+n][k] fp16 (n==15 zero pad). Coalesced read + LDS transpose. ----
__global__ __launch_bounds__(256)
void kprepW(const float* __restrict__ nw, __fp16* __restrict__ WrT) {
  __shared__ float Ls[128][16];
  const int tid = threadIdx.x;
  const int t  = blockIdx.x >> 4;
  const int k0 = (blockIdx.x & 15) * 128;
  const float* base = nw + ((size_t)t * INDIM + k0) * 15;
  #pragma unroll
  for (int i = 0; i < 8; i++) {
    int fl = tid + 256 * i;            // 0..2047, need < 1920
    if (fl < 1920) {
      float v = base[fl];
      int kk = (int)(((unsigned)fl * 8739u) >> 17);   // fl / 15
      int n  = fl - 15 * kk;
      Ls[kk][n] = v;
    }
  }
  __syncthreads();
  const int n  = tid >> 4;             // 0..15
  const int kc = tid & 15;             // 8-wide k chunk
  half8 h = {};
  if (n < 15) {
    #pragma unroll
    for (int j = 0; j < 8; j++) h[j] = (__fp16)Ls[kc * 8 + j][n];
  }
  *(half8*)(WrT + (size_t)(16 * t + n) * INDIM + k0 + kc * 8) = h;
}

// ---- prep: LWrT[o][16t+l] fp16. Coalesced read + LDS transpose. 64 blocks. ----
__global__ __launch_bounds__(256)
void kprepL(const float* __restrict__ lw, __fp16* __restrict__ LWrT) {
  __shared__ float Ls[128][17];
  const int tid = threadIdx.x;
  const int t  = blockIdx.x >> 2;           // 0..15
  const int o0 = (blockIdx.x & 3) * 128;    // 0..384
  const float* base = lw + ((size_t)t * OUTD + o0) * 16;
  #pragma unroll
  for (int i = 0; i < 8; i++) {
    int fl = tid + 256 * i;                 // 0..2047 = 128 o x 16 l, coalesced
    Ls[fl >> 4][fl & 15] = base[fl];
  }
  __syncthreads();
  const int ol = tid >> 1;                  // 0..127
  const int h  = tid & 1;                   // half
  half8 v;
  #pragma unroll
  for (int j = 0; j < 8; j++) v[j] = (__fp16)Ls[ol][8 * h + j];
  *(half8*)(LWrT + (size_t)(o0 + ol) * NC + 16 * t + 8 * h) = v;
}

// ---- fused: barrier-free GEMM1 (X,W direct->reg) -> gates -> probs -> GEMM2 ----
__global__ __launch_bounds__(512, 1)
void kfused(const float* __restrict__ x, const __fp16* __restrict__ WrT,
            const __fp16* __restrict__ LWrT, float* __restrict__ out) {
  __shared__ float  As[BM * NC];               // 32 KB
  __shared__ __fp16 Ps[BM * NC];               // 16 KB

  const int tid  = threadIdx.x;
  const int lane = tid & 63;
  const int wv   = tid >> 6;       // 0..7
  const int l15  = lane & 15;
  const int lg   = lane >> 4;      // 0..3
  const int r0   = blockIdx.x * BM;

  // A-frag source: lane reads 8 consecutive fp32 of row (r0+l15[+16]) at k = k0+lg*8.
  // One wave instr = 16 rows x 128B = 16 full cachelines, 4 lanes/line: fully coalesced.
  const float*  xr0 = x + (size_t)(r0 + l15) * INDIM + lg * 8;
  const float*  xr1 = xr0 + (size_t)16 * INDIM;
  const __fp16* wb0 = WrT + (size_t)(32 * wv + l15) * INDIM + lg * 8;
  const __fp16* wb1 = wb0 + (size_t)16 * INDIM;

  f32x4 acc1[2][2] = {};

  // ---- GEMM1: no LDS, no barriers; waves slip freely, loads pipeline ----
  #pragma unroll 8
  for (int k0 = 0; k0 < INDIM; k0 += 32) {
    float4 a0 = *(const float4*)(xr0 + k0);
    float4 a1 = *(const float4*)(xr0 + k0 + 4);
    float4 b0 = *(const float4*)(xr1 + k0);
    float4 b1 = *(const float4*)(xr1 + k0 + 4);
    half8  bf0 = *(const half8*)(wb0 + k0);
    half8  bf1 = *(const half8*)(wb1 + k0);
    half8  af0 = cvt8(a0, a1);
    half8  af1 = cvt8(b0, b1);
    acc1[0][0] = __builtin_amdgcn_mfma_f32_16x16x32_f16(af0, bf0, acc1[0][0], 0, 0, 0);
    acc1[0][1] = __builtin_amdgcn_mfma_f32_16x16x32_f16(af0, bf1, acc1[0][1], 0, 0, 0);
    acc1[1][0] = __builtin_amdgcn_mfma_f32_16x16x32_f16(af1, bf0, acc1[1][0], 0, 0, 0);
    acc1[1][1] = __builtin_amdgcn_mfma_f32_16x16x32_f16(af1, bf1, acc1[1][1], 0, 0, 0);
  }

  // write A tile: C layout col=lane&15, row=4*(lane>>4)+reg  [m89-verified]
  #pragma unroll
  for (int mt = 0; mt < 2; mt++)
    #pragma unroll
    for (int nt = 0; nt < 2; nt++)
      #pragma unroll
      for (int i = 0; i < 4; i++)
        As[(16 * mt + 4 * lg + i) * NC + 32 * wv + 16 * nt + l15] = acc1[mt][nt][i];
  __syncthreads();

  // gates + leaf probs: one thread per (row, tree)
  {
    const int row = tid >> 4, tr = tid & 15;
    float av[16];
    #pragma unroll
    for (int q = 0; q < 4; q++) {
      f32x4 v = *(const f32x4*)&As[row * NC + tr * 16 + 4 * q];
      av[4 * q + 0] = v[0]; av[4 * q + 1] = v[1];
      av[4 * q + 2] = v[2]; av[4 * q + 3] = v[3];
    }
    float sg[15];
    #pragma unroll
    for (int m = 0; m < 15; m++) {
      float t = fminf(fmaxf(av[m] + 0.5f, 0.f), 1.f);   // SMOOTH_STEP_PARAM = 1
      sg[m] = t * t * (3.f - 2.f * t);
    }
    float p[16];
    #pragma unroll
    for (int l = 0; l < 16; l++) {
      float pr = 1.f; int node = 0;
      #pragma unroll
      for (int L = 0; L < 4; L++) {
        int bit = (l >> (3 - L)) & 1;  // 0 = left (s), 1 = right (1-s)
        pr *= bit ? (1.f - sg[node]) : sg[node];
        node = 2 * node + 1 + bit;
      }
      p[l] = pr;
    }
    half8 h0, h1;
    #pragma unroll
    for (int j = 0; j < 8; j++) { h0[j] = (__fp16)p[j]; h1[j] = (__fp16)p[8 + j]; }
    const int base = row * NC + tr * 16;
    const int swz  = (row & 7) << 3;
    *(half8*)&Ps[(base) ^ swz]     = h0;
    *(half8*)&Ps[(base + 8) ^ swz] = h1;
  }
  __syncthreads();

  // GEMM2: out[32][512] = P[32][256] * LWrT^T ; B direct from L2/L3 (reuse == 1)
  f32x4 acc2[2][4] = {};
  const __fp16* lbase = LWrT + (size_t)(64 * wv + l15) * NC + lg * 8;
  #pragma unroll
  for (int kc = 0; kc < 2; kc++) {
    half8 bf2[4][4];
    #pragma unroll
    for (int nt = 0; nt < 4; nt++)
      #pragma unroll
      for (int ks = 0; ks < 4; ks++)
        bf2[nt][ks] = *(const half8*)(lbase + (size_t)nt * 16 * NC + kc * 128 + ks * 32);
    #pragma unroll
    for (int ks = 0; ks < 4; ks++) {
      half8 af[2];
      #pragma unroll
      for (int mt = 0; mt < 2; mt++) {
        const int r = l15 + 16 * mt;
        const int e = (r * NC + kc * 128 + ks * 32 + lg * 8) ^ ((r & 7) << 3);
        af[mt] = *(const half8*)&Ps[e];
      }
      #pragma unroll
      for (int mt = 0; mt < 2; mt++)
        #pragma unroll
        for (int nt = 0; nt < 4; nt++)
          acc2[mt][nt] = __builtin_amdgcn_mfma_f32_16x16x32_f16(af[mt], bf2[nt][ks], acc2[mt][nt], 0, 0, 0);
    }
  }
  #pragma unroll
  for (int mt = 0; mt < 2; mt++)
    #pragma unroll
    for (int nt = 0; nt < 4; nt++)
      #pragma unroll
      for (int i = 0; i < 4; i++)
        out[(size_t)(r0 + 16 * mt + 4 * lg + i) * OUTD + 64 * wv + 16 * nt + l15] = acc2[mt][nt][i];
}

extern "C" void kernel_launch(void* const* d_in, const int* in_sizes, int n_in,
                              void* d_out, int out_size, void* d_ws, size_t ws_size,
                              hipStream_t stream) {
  const float* x  = (const float*)d_in[0];
  const float* nw = (const float*)d_in[1];
  const float* lw = (const float*)d_in[2];
  float* out = (float*)d_out;

  __fp16* WrT  = (__fp16*)d_ws;                                   // 1 MB
  __fp16* LWrT = (__fp16*)((char*)d_ws + (size_t)NC * INDIM * 2); // 256 KB

  hipLaunchKernelGGL(kprepW, dim3(256), dim3(256), 0, stream, nw, WrT);
  hipLaunchKernelGGL(kprepL, dim3(64),  dim3(256), 0, stream, lw, LWrT);
  hipLaunchKernelGGL(kfused, dim3(BATCH / BM), dim3(512), 0, stream, x, WrT, LWrT, out);
}

// Round 7
// 172.734 us; speedup vs baseline: 1.0832x; 1.0832x over previous
//
#include <hip/hip_runtime.h>
#include <cstdint>
#include <cstddef>

typedef __fp16 half8 __attribute__((ext_vector_type(8)));
typedef float  f32x4 __attribute__((ext_vector_type(4)));

#define BATCH 8192
#define INDIM 2048
#define OUTD  512
#define NC    256      // 16 trees * 16 (15 nodes + 1 zero pad)
#define BM    16       // rows per block -> 512 blocks = 2/CU (the TLP fix)
#define BK    256      // GEMM1 k-chunk
#define NCH   (INDIM / BK)   // 8 chunks

__device__ __forceinline__ half8 cvt8(float4 a, float4 b) {
  half8 h;
  h[0] = (__fp16)a.x; h[1] = (__fp16)a.y; h[2] = (__fp16)a.z; h[3] = (__fp16)a.w;
  h[4] = (__fp16)b.x; h[5] = (__fp16)b.y; h[6] = (__fp16)b.z; h[7] = (__fp16)b.w;
  return h;
}

// ---- prep: WrT[16t+n][k] fp16 (n==15 zero pad). Coalesced read + LDS transpose. ----
__global__ __launch_bounds__(256)
void kprepW(const float* __restrict__ nw, __fp16* __restrict__ WrT) {
  __shared__ float Ls[128][16];
  const int tid = threadIdx.x;
  const int t  = blockIdx.x >> 4;
  const int k0 = (blockIdx.x & 15) * 128;
  const float* base = nw + ((size_t)t * INDIM + k0) * 15;
  #pragma unroll
  for (int i = 0; i < 8; i++) {
    int fl = tid + 256 * i;            // 0..2047, need < 1920
    if (fl < 1920) {
      float v = base[fl];
      int kk = (int)(((unsigned)fl * 8739u) >> 17);   // fl / 15
      int n  = fl - 15 * kk;
      Ls[kk][n] = v;
    }
  }
  __syncthreads();
  const int n  = tid >> 4;             // 0..15
  const int kc = tid & 15;             // 8-wide k chunk
  half8 h = {};
  if (n < 15) {
    #pragma unroll
    for (int j = 0; j < 8; j++) h[j] = (__fp16)Ls[kc * 8 + j][n];
  }
  *(half8*)(WrT + (size_t)(16 * t + n) * INDIM + k0 + kc * 8) = h;
}

// ---- prep: LWrT[o][16t+l] fp16. Coalesced read + LDS transpose. 64 blocks. ----
__global__ __launch_bounds__(256)
void kprepL(const float* __restrict__ lw, __fp16* __restrict__ LWrT) {
  __shared__ float Ls[128][17];
  const int tid = threadIdx.x;
  const int t  = blockIdx.x >> 2;           // 0..15
  const int o0 = (blockIdx.x & 3) * 128;    // 0..384
  const float* base = lw + ((size_t)t * OUTD + o0) * 16;
  #pragma unroll
  for (int i = 0; i < 8; i++) {
    int fl = tid + 256 * i;                 // 0..2047 = 128 o x 16 l, coalesced
    Ls[fl >> 4][fl & 15] = base[fl];
  }
  __syncthreads();
  const int ol = tid >> 1;                  // 0..127
  const int h  = tid & 1;                   // half
  half8 v;
  #pragma unroll
  for (int j = 0; j < 8; j++) v[j] = (__fp16)Ls[ol][8 * h + j];
  *(half8*)(LWrT + (size_t)(o0 + ol) * NC + 16 * t + 8 * h) = v;
}

// ---- fused: GEMM1 -> gates -> probs -> GEMM2 ; BM=16, 2 blocks/CU ----
__global__ __launch_bounds__(512, 4)
void kfused(const float* __restrict__ x, const __fp16* __restrict__ WrT,
            const __fp16* __restrict__ LWrT, float* __restrict__ out) {
  __shared__ char   uni[BM * NC * 4];          // 16 KB: Xs dbuf (2 x 8 KB) | As (16 KB)
  __shared__ __fp16 Ps[BM * NC];               // 8 KB
  __fp16* Xs = (__fp16*)uni;                   // elem (r*BK + k) ^ ((r&7)<<3), per buffer
  float*  As = (float*)uni;

  const int tid  = threadIdx.x;
  const int lane = tid & 63;
  const int wv   = tid >> 6;       // 0..7
  const int l15  = lane & 15;
  const int lg   = lane >> 4;      // 0..3
  const int r0   = blockIdx.x * BM;
  const int sr   = tid >> 5;       // staging row 0..15
  const int seg  = tid & 31;       // 8-float segment within BK

  const float*  xrow = x + (size_t)(r0 + sr) * INDIM + seg * 8;
  const int sE = (sr * BK + seg * 8) ^ ((sr & 7) << 3);

  // GEMM1: wave wv owns cols 32wv..32wv+31 (2 nt tiles of 16)
  const __fp16* wb0 = WrT + (size_t)(32 * wv + l15) * INDIM + lg * 8;
  const __fp16* wb1 = wb0 + (size_t)16 * INDIM;

  f32x4 acc1[2] = {};
  float4 px0, px1;

  // prologue: stage chunk 0
  {
    float4 a = *(const float4*)(xrow);
    float4 b = *(const float4*)(xrow + 4);
    *(half8*)&Xs[sE] = cvt8(a, b);
  }
  __syncthreads();

  #pragma unroll 1
  for (int ch = 0; ch < NCH; ++ch) {
    const int cur = ch & 1;
    const bool more = (ch + 1 < NCH);
    if (more) {
      const float* p = xrow + (ch + 1) * BK;
      px0 = *(const float4*)(p);
      px1 = *(const float4*)(p + 4);
    }
    #pragma unroll
    for (int ks = 0; ks < BK / 32; ks++) {
      half8 bf0 = *(const half8*)(wb0 + ch * BK + ks * 32);
      half8 bf1 = *(const half8*)(wb1 + ch * BK + ks * 32);
      const int e = (l15 * BK + ks * 32 + lg * 8) ^ ((l15 & 7) << 3);
      half8 af = *(const half8*)&Xs[cur * (BM * BK) + e];
      acc1[0] = __builtin_amdgcn_mfma_f32_16x16x32_f16(af, bf0, acc1[0], 0, 0, 0);
      acc1[1] = __builtin_amdgcn_mfma_f32_16x16x32_f16(af, bf1, acc1[1], 0, 0, 0);
    }
    if (more) {
      *(half8*)&Xs[(cur ^ 1) * (BM * BK) + sE] = cvt8(px0, px1);
    }
    __syncthreads();
  }

  // write A tile: C layout col=lane&15, row=4*(lane>>4)+reg  [m89-verified]
  #pragma unroll
  for (int nt = 0; nt < 2; nt++)
    #pragma unroll
    for (int i = 0; i < 4; i++)
      As[(4 * lg + i) * NC + 32 * wv + 16 * nt + l15] = acc1[nt][i];
  __syncthreads();

  // gates + leaf probs: threads 0..255, one per (row, tree)
  if (tid < 256) {
    const int row = tid >> 4, tr = tid & 15;
    float av[16];
    #pragma unroll
    for (int q = 0; q < 4; q++) {
      f32x4 v = *(const f32x4*)&As[row * NC + tr * 16 + 4 * q];
      av[4 * q + 0] = v[0]; av[4 * q + 1] = v[1];
      av[4 * q + 2] = v[2]; av[4 * q + 3] = v[3];
    }
    float sg[15];
    #pragma unroll
    for (int m = 0; m < 15; m++) {
      float t = fminf(fmaxf(av[m] + 0.5f, 0.f), 1.f);   // SMOOTH_STEP_PARAM = 1
      sg[m] = t * t * (3.f - 2.f * t);
    }
    float p[16];
    #pragma unroll
    for (int l = 0; l < 16; l++) {
      float pr = 1.f; int node = 0;
      #pragma unroll
      for (int L = 0; L < 4; L++) {
        int bit = (l >> (3 - L)) & 1;  // 0 = left (s), 1 = right (1-s)
        pr *= bit ? (1.f - sg[node]) : sg[node];
        node = 2 * node + 1 + bit;
      }
      p[l] = pr;
    }
    half8 h0, h1;
    #pragma unroll
    for (int j = 0; j < 8; j++) { h0[j] = (__fp16)p[j]; h1[j] = (__fp16)p[8 + j]; }
    const int base = row * NC + tr * 16;
    const int swz  = (row & 7) << 3;
    *(half8*)&Ps[(base) ^ swz]     = h0;
    *(half8*)&Ps[(base + 8) ^ swz] = h1;
  }
  __syncthreads();

  // GEMM2: out[16][512] = P[16][256] * LWrT^T ; wave wv owns cols 64wv..64wv+63
  f32x4 acc2[4] = {};
  const __fp16* lbase = LWrT + (size_t)(64 * wv + l15) * NC + lg * 8;
  #pragma unroll
  for (int kc = 0; kc < 2; kc++) {
    #pragma unroll
    for (int ks = 0; ks < 4; ks++) {
      const int e = (l15 * NC + kc * 128 + ks * 32 + lg * 8) ^ ((l15 & 7) << 3);
      half8 af = *(const half8*)&Ps[e];
      #pragma unroll
      for (int nt = 0; nt < 4; nt++) {
        half8 bf = *(const half8*)(lbase + (size_t)nt * 16 * NC + kc * 128 + ks * 32);
        acc2[nt] = __builtin_amdgcn_mfma_f32_16x16x32_f16(af, bf, acc2[nt], 0, 0, 0);
      }
    }
  }
  #pragma unroll
  for (int nt = 0; nt < 4; nt++)
    #pragma unroll
    for (int i = 0; i < 4; i++)
      out[(size_t)(r0 + 4 * lg + i) * OUTD + 64 * wv + 16 * nt + l15] = acc2[nt][i];
}

extern "C" void kernel_launch(void* const* d_in, const int* in_sizes, int n_in,
                              void* d_out, int out_size, void* d_ws, size_t ws_size,
                              hipStream_t stream) {
  const float* x  = (const float*)d_in[0];
  const float* nw = (const float*)d_in[1];
  const float* lw = (const float*)d_in[2];
  float* out = (float*)d_out;

  __fp16* WrT  = (__fp16*)d_ws;                                   // 1 MB
  __fp16* LWrT = (__fp16*)((char*)d_ws + (size_t)NC * INDIM * 2); // 256 KB

  hipLaunchKernelGGL(kprepW, dim3(256), dim3(256), 0, stream, nw, WrT);
  hipLaunchKernelGGL(kprepL, dim3(64),  dim3(256), 0, stream, lw, LWrT);
  hipLaunchKernelGGL(kfused, dim3(BATCH / BM), dim3(512), 0, stream, x, WrT, LWrT, out);
}

// Round 8
// 154.322 us; speedup vs baseline: 1.2124x; 1.1193x over previous
//
#include <hip/hip_runtime.h>
#include <cstdint>
#include <cstddef>

typedef __fp16 half8 __attribute__((ext_vector_type(8)));
typedef float  f32x4 __attribute__((ext_vector_type(4)));

#define BATCH 8192
#define INDIM 2048
#define OUTD  512
#define NC    256      // 16 trees * 16 (15 nodes + 1 zero pad)
#define BM    32       // rows per k1 block
#define KS    4        // K-split -> 1024 k1 blocks = 4/CU
#define KH    (INDIM / KS)   // 512
#define BK    128
#define NCH1  (KH / BK)      // 4 chunks
#define BM2   16       // rows per k2 block

__device__ __forceinline__ half8 cvt8(float4 a, float4 b) {
  half8 h;
  h[0] = (__fp16)a.x; h[1] = (__fp16)a.y; h[2] = (__fp16)a.z; h[3] = (__fp16)a.w;
  h[4] = (__fp16)b.x; h[5] = (__fp16)b.y; h[6] = (__fp16)b.z; h[7] = (__fp16)b.w;
  return h;
}

// ---- prep: WrT[16t+n][k] fp16 (n==15 zero pad). Coalesced read + LDS transpose. ----
__global__ __launch_bounds__(256)
void kprepW(const float* __restrict__ nw, __fp16* __restrict__ WrT) {
  __shared__ float Ls[128][16];
  const int tid = threadIdx.x;
  const int t  = blockIdx.x >> 4;
  const int k0 = (blockIdx.x & 15) * 128;
  const float* base = nw + ((size_t)t * INDIM + k0) * 15;
  #pragma unroll
  for (int i = 0; i < 8; i++) {
    int fl = tid + 256 * i;            // 0..2047, need < 1920
    if (fl < 1920) {
      float v = base[fl];
      int kk = (int)(((unsigned)fl * 8739u) >> 17);   // fl / 15
      int n  = fl - 15 * kk;
      Ls[kk][n] = v;
    }
  }
  __syncthreads();
  const int n  = tid >> 4;             // 0..15
  const int kc = tid & 15;             // 8-wide k chunk
  half8 h = {};
  if (n < 15) {
    #pragma unroll
    for (int j = 0; j < 8; j++) h[j] = (__fp16)Ls[kc * 8 + j][n];
  }
  *(half8*)(WrT + (size_t)(16 * t + n) * INDIM + k0 + kc * 8) = h;
}

// ---- prep: LWrT[o][16t+l] fp16. Coalesced read + LDS transpose. 64 blocks. ----
__global__ __launch_bounds__(256)
void kprepL(const float* __restrict__ lw, __fp16* __restrict__ LWrT) {
  __shared__ float Ls[128][17];
  const int tid = threadIdx.x;
  const int t  = blockIdx.x >> 2;           // 0..15
  const int o0 = (blockIdx.x & 3) * 128;    // 0..384
  const float* base = lw + ((size_t)t * OUTD + o0) * 16;
  #pragma unroll
  for (int i = 0; i < 8; i++) {
    int fl = tid + 256 * i;                 // 0..2047 = 128 o x 16 l, coalesced
    Ls[fl >> 4][fl & 15] = base[fl];
  }
  __syncthreads();
  const int ol = tid >> 1;                  // 0..127
  const int h  = tid & 1;                   // half
  half8 v;
  #pragma unroll
  for (int j = 0; j < 8; j++) v[j] = (__fp16)Ls[ol][8 * h + j];
  *(half8*)(LWrT + (size_t)(o0 + ol) * NC + 16 * t + 8 * h) = v;
}

// ---- k1: K-split GEMM1. grid 1024 = 256 row-tiles x 4 k-ranges; 4 blocks/CU. ----
__global__ __launch_bounds__(512, 4)
void k1(const float* __restrict__ x, const __fp16* __restrict__ WrT,
        float* __restrict__ Apart) {
  __shared__ __fp16 Xs[2 * BM * BK];   // 16 KB double-buffered X tile

  const int tid  = threadIdx.x;
  const int lane = tid & 63;
  const int wv   = tid >> 6;       // 0..7, owns cols 32wv..32wv+31
  const int l15  = lane & 15;
  const int lg   = lane >> 4;      // 0..3
  const int rt   = blockIdx.x & 255;
  const int kh   = blockIdx.x >> 8;
  const int r0   = rt * BM;
  const int kb   = kh * KH;
  const int sr   = tid >> 4;       // staging row 0..31
  const int sk   = tid & 15;       // staging 8-float octet

  const float*  xrow = x + (size_t)(r0 + sr) * INDIM + kb + sk * 8;
  const int sE = (sr * BK + sk * 8) ^ ((sr & 7) << 3);
  const __fp16* wb0 = WrT + (size_t)(32 * wv + l15) * INDIM + kb + lg * 8;
  const __fp16* wb1 = wb0 + (size_t)16 * INDIM;

  f32x4 acc1[2][2] = {};
  float4 px0, px1;

  // prologue: stage chunk 0
  {
    float4 a = *(const float4*)(xrow);
    float4 b = *(const float4*)(xrow + 4);
    *(half8*)&Xs[sE] = cvt8(a, b);
  }
  __syncthreads();

  #pragma unroll 1
  for (int ch = 0; ch < NCH1; ++ch) {
    const int cur = ch & 1;
    const bool more = (ch + 1 < NCH1);
    if (more) {
      const float* p = xrow + (ch + 1) * BK;
      px0 = *(const float4*)(p);
      px1 = *(const float4*)(p + 4);
    }
    #pragma unroll
    for (int ks = 0; ks < BK / 32; ks++) {
      half8 bf0 = *(const half8*)(wb0 + ch * BK + ks * 32);
      half8 bf1 = *(const half8*)(wb1 + ch * BK + ks * 32);
      half8 af[2];
      #pragma unroll
      for (int mt = 0; mt < 2; mt++) {
        const int r = l15 + 16 * mt;
        const int e = (r * BK + ks * 32 + lg * 8) ^ ((r & 7) << 3);
        af[mt] = *(const half8*)&Xs[cur * (BM * BK) + e];
      }
      acc1[0][0] = __builtin_amdgcn_mfma_f32_16x16x32_f16(af[0], bf0, acc1[0][0], 0, 0, 0);
      acc1[0][1] = __builtin_amdgcn_mfma_f32_16x16x32_f16(af[0], bf1, acc1[0][1], 0, 0, 0);
      acc1[1][0] = __builtin_amdgcn_mfma_f32_16x16x32_f16(af[1], bf0, acc1[1][0], 0, 0, 0);
      acc1[1][1] = __builtin_amdgcn_mfma_f32_16x16x32_f16(af[1], bf1, acc1[1][1], 0, 0, 0);
    }
    if (more) {
      *(half8*)&Xs[(cur ^ 1) * (BM * BK) + sE] = cvt8(px0, px1);
    }
    __syncthreads();
  }

  // write partial A: C layout col=lane&15, row=4*(lane>>4)+reg  [m89-verified]
  float* ap = Apart + ((size_t)kh * BATCH + r0) * NC;
  #pragma unroll
  for (int mt = 0; mt < 2; mt++)
    #pragma unroll
    for (int nt = 0; nt < 2; nt++)
      #pragma unroll
      for (int i = 0; i < 4; i++)
        ap[(size_t)(16 * mt + 4 * lg + i) * NC + 32 * wv + 16 * nt + l15] = acc1[mt][nt][i];
}

// ---- k2: sum K-partials -> gates -> leaf probs -> GEMM2. 512 blocks x 256 thr. ----
__global__ __launch_bounds__(256)
void k2(const float* __restrict__ Apart, const __fp16* __restrict__ LWrT,
        float* __restrict__ out) {
  __shared__ __fp16 Ps[BM2 * NC];              // 8 KB

  const int tid = threadIdx.x;
  const int r0  = blockIdx.x * BM2;

  // gates + leaf probs: one thread per (row, tree)
  {
    const int row = tid >> 4, tr = tid & 15;
    float av[16];
    #pragma unroll
    for (int m = 0; m < 16; m++) av[m] = 0.f;
    #pragma unroll
    for (int h = 0; h < KS; ++h) {
      const float* ap = Apart + ((size_t)h * BATCH + r0 + row) * NC + tr * 16;
      #pragma unroll
      for (int q = 0; q < 4; q++) {
        f32x4 v = *(const f32x4*)(ap + 4 * q);
        av[4 * q + 0] += v[0]; av[4 * q + 1] += v[1];
        av[4 * q + 2] += v[2]; av[4 * q + 3] += v[3];
      }
    }
    float sg[15];
    #pragma unroll
    for (int m = 0; m < 15; m++) {
      float t = fminf(fmaxf(av[m] + 0.5f, 0.f), 1.f);   // SMOOTH_STEP_PARAM = 1
      sg[m] = t * t * (3.f - 2.f * t);
    }
    float p[16];
    #pragma unroll
    for (int l = 0; l < 16; l++) {
      float pr = 1.f; int node = 0;
      #pragma unroll
      for (int L = 0; L < 4; L++) {
        int bit = (l >> (3 - L)) & 1;  // 0 = left (s), 1 = right (1-s)
        pr *= bit ? (1.f - sg[node]) : sg[node];
        node = 2 * node + 1 + bit;
      }
      p[l] = pr;
    }
    half8 h0, h1;
    #pragma unroll
    for (int j = 0; j < 8; j++) { h0[j] = (__fp16)p[j]; h1[j] = (__fp16)p[8 + j]; }
    const int base = row * NC + tr * 16;
    const int swz  = (row & 7) << 3;
    *(half8*)&Ps[(base) ^ swz]     = h0;
    *(half8*)&Ps[(base + 8) ^ swz] = h1;
  }
  __syncthreads();

  // GEMM2: out[16][512] = P[16][256] * LWrT^T ; 4 waves, wave owns 128 cols
  const int lane = tid & 63;
  const int wv   = tid >> 6;       // 0..3
  const int l15  = lane & 15;
  const int lg   = lane >> 4;
  f32x4 acc2[8] = {};
  const __fp16* lbase = LWrT + (size_t)(128 * wv + l15) * NC + lg * 8;
  #pragma unroll
  for (int kc = 0; kc < 2; kc++) {
    #pragma unroll
    for (int ks = 0; ks < 4; ks++) {
      const int e = (l15 * NC + kc * 128 + ks * 32 + lg * 8) ^ ((l15 & 7) << 3);
      half8 af = *(const half8*)&Ps[e];
      #pragma unroll
      for (int nt = 0; nt < 8; nt++) {
        half8 bf = *(const half8*)(lbase + (size_t)nt * 16 * NC + kc * 128 + ks * 32);
        acc2[nt] = __builtin_amdgcn_mfma_f32_16x16x32_f16(af, bf, acc2[nt], 0, 0, 0);
      }
    }
  }
  #pragma unroll
  for (int nt = 0; nt < 8; nt++)
    #pragma unroll
    for (int i = 0; i < 4; i++)
      out[(size_t)(r0 + 4 * lg + i) * OUTD + 128 * wv + 16 * nt + l15] = acc2[nt][i];
}

extern "C" void kernel_launch(void* const* d_in, const int* in_sizes, int n_in,
                              void* d_out, int out_size, void* d_ws, size_t ws_size,
                              hipStream_t stream) {
  const float* x  = (const float*)d_in[0];
  const float* nw = (const float*)d_in[1];
  const float* lw = (const float*)d_in[2];
  float* out = (float*)d_out;

  char* ws = (char*)d_ws;
  __fp16* WrT   = (__fp16*)ws;                                  // 1 MB
  __fp16* LWrT  = (__fp16*)(ws + (size_t)NC * INDIM * 2);       // 256 KB
  float*  Apart = (float*)(ws + (size_t)NC * INDIM * 2 + (size_t)NC * OUTD * 2); // 32 MB

  hipLaunchKernelGGL(kprepW, dim3(256), dim3(256), 0, stream, nw, WrT);
  hipLaunchKernelGGL(kprepL, dim3(64),  dim3(256), 0, stream, lw, LWrT);
  hipLaunchKernelGGL(k1, dim3((BATCH / BM) * KS), dim3(512), 0, stream, x, WrT, Apart);
  hipLaunchKernelGGL(k2, dim3(BATCH / BM2), dim3(256), 0, stream, Apart, LWrT, out);
}